// Round 4
// baseline (1404.189 us; speedup 1.0000x reference)
//
#include <hip/hip_runtime.h>
#include <hip/hip_bf16.h>

#define B_ 8
#define C_ 64
#define S_ 112
#define HW_ 12544      // 112*112
#define NG_ 3136       // 56*56
#define TG_ 56
#define PA_ 196        // 14*14
#define PApad_ 208     // padded pitch for W^T (multiple of 4 for float4)
#define EPS_ 1e-5f

// ---------------- ws layout (floats) ----------------
// Total footprint ~99 MB (was 157 MB): HP aliases Q (dead after k_pqk),
// HG aliases K (dead after k_pqk). Stream order guarantees safety:
//   pqk(Q,K) -> psoftmax -> pav(V,WT -> HP=Qregion) -> gattn(QG,KG,VG -> HG=Kregion) -> final(HP,HG)
static constexpr size_t OFF_STATS = 0;                               // 64 (sum,sumsq per batch)
static constexpr size_t OFF_SP    = 64;                              // B*196*196 patch logits (atomically accumulated)
static constexpr size_t OFF_WQT   = OFF_SP + (size_t)B_*PA_*PA_;     // 4096 transposed weights
static constexpr size_t OFF_WKT   = OFF_WQT + 4096;
static constexpr size_t OFF_WVT   = OFF_WKT + 4096;
static constexpr size_t OFF_WPT   = OFF_WVT + 4096;
static constexpr size_t OFF_WT    = OFF_WPT + 4096;                  // B*196*208 softmaxed W^T
static constexpr size_t OFF_Q     = OFF_WT + (size_t)B_*PA_*PApad_;
static constexpr size_t OFF_K     = OFF_Q + (size_t)B_*C_*HW_;
static constexpr size_t OFF_V     = OFF_K + (size_t)B_*C_*HW_;
static constexpr size_t OFF_QG    = OFF_V + (size_t)B_*C_*HW_;
static constexpr size_t OFF_KG    = OFF_QG + (size_t)B_*C_*NG_;
static constexpr size_t OFF_VG    = OFF_KG + (size_t)B_*C_*NG_;
static constexpr size_t OFF_HP    = OFF_Q;                           // alias: Q dead after k_pqk
static constexpr size_t OFF_HG    = OFF_K;                           // alias: K dead after k_pqk
// end of ws = OFF_VG + B*C*NG = 24,734,400 floats ~= 99 MB

// ---------------- weight transpose (once per launch, tiny) ----------------
__global__ void k_wtrans(const float* __restrict__ wq, const float* __restrict__ wk,
                         const float* __restrict__ wv, const float* __restrict__ wp,
                         float* __restrict__ qT, float* __restrict__ kT,
                         float* __restrict__ vT, float* __restrict__ pT) {
  int idx = blockIdx.x * 256 + threadIdx.x;
  if (idx < 4096) {
    int o = idx >> 6, c = idx & 63;
    int t = c * 64 + o;
    qT[t] = wq[idx]; kT[t] = wk[idx]; vT[t] = wv[idx]; pT[t] = wp[idx];
  }
}

// ---------------- GroupNorm stats: sum & sumsq per batch ----------------
__global__ __launch_bounds__(256) void k_gnstats(const float* __restrict__ x,
                                                 float* __restrict__ stats) {
  int blk = blockIdx.x;            // b*64 + c
  int b = blk >> 6;
  const float4* p = (const float4*)(x + (size_t)blk * HW_);
  float s = 0.f, s2 = 0.f;
  for (int t = threadIdx.x; t < HW_ / 4; t += 256) {
    float4 v = p[t];
    s  += v.x + v.y + v.z + v.w;
    s2 += v.x*v.x + v.y*v.y + v.z*v.z + v.w*v.w;
  }
  for (int o = 32; o > 0; o >>= 1) { s += __shfl_down(s, o); s2 += __shfl_down(s2, o); }
  __shared__ float ls[4], ls2[4];
  int wid = threadIdx.x >> 6, lane = threadIdx.x & 63;
  if (lane == 0) { ls[wid] = s; ls2[wid] = s2; }
  __syncthreads();
  if (threadIdx.x == 0) {
    float a = 0.f, a2 = 0.f;
    for (int w = 0; w < 4; ++w) { a += ls[w]; a2 += ls2[w]; }
    atomicAdd(&stats[b * 2], a);
    atomicAdd(&stats[b * 2 + 1], a2);
  }
}

// ---------------- fused GroupNorm + QKV conv1x1 ----------------
__global__ __launch_bounds__(256) void k_qkv(
    const float* __restrict__ x, const float* __restrict__ stats,
    const float* __restrict__ gnw, const float* __restrict__ gnb,
    const float* __restrict__ wqT, const float* __restrict__ wkT, const float* __restrict__ wvT,
    const float* __restrict__ bq, const float* __restrict__ bk, const float* __restrict__ bv,
    float* __restrict__ q, float* __restrict__ k, float* __restrict__ v) {
  __shared__ float wqs[4096], wks[4096], wvs[4096], xt[4096];
  int b = blockIdx.x / PA_, tile = blockIdx.x % PA_;
  int s0 = tile * 64;
  int tid = threadIdx.x;
  for (int idx = tid; idx < 4096; idx += 256) {
    wqs[idx] = wqT[idx]; wks[idx] = wkT[idx]; wvs[idx] = wvT[idx];
  }
  float n  = (float)(C_ * HW_);
  float mu = stats[2 * b] / n;
  float var = stats[2 * b + 1] / n - mu * mu;
  float rs = rsqrtf(var + EPS_);
  for (int idx = tid; idx < 4096; idx += 256) {
    int c = idx >> 6, p = idx & 63;
    float val = x[((size_t)(b * 64 + c)) * HW_ + s0 + p];
    xt[idx] = (val - mu) * rs * gnw[c] + gnb[c];
  }
  __syncthreads();
  int o = tid & 63, g = tid >> 6;
  float aq[16], ak[16], av[16];
  float bqv = bq[o], bkv = bk[o], bvv = bv[o];
#pragma unroll
  for (int i = 0; i < 16; ++i) { aq[i] = bqv; ak[i] = bkv; av[i] = bvv; }
  for (int c = 0; c < 64; ++c) {
    float wqv = wqs[c * 64 + o], wkv = wks[c * 64 + o], wvv = wvs[c * 64 + o];
    const float4* xr = (const float4*)(xt + c * 64 + g * 16);
#pragma unroll
    for (int i4 = 0; i4 < 4; ++i4) {
      float4 xv = xr[i4];
      aq[i4*4+0] += wqv*xv.x; aq[i4*4+1] += wqv*xv.y; aq[i4*4+2] += wqv*xv.z; aq[i4*4+3] += wqv*xv.w;
      ak[i4*4+0] += wkv*xv.x; ak[i4*4+1] += wkv*xv.y; ak[i4*4+2] += wkv*xv.z; ak[i4*4+3] += wkv*xv.w;
      av[i4*4+0] += wvv*xv.x; av[i4*4+1] += wvv*xv.y; av[i4*4+2] += wvv*xv.z; av[i4*4+3] += wvv*xv.w;
    }
  }
  size_t base = ((size_t)(b * 64 + o)) * HW_ + s0 + g * 16;
  float4* qd = (float4*)(q + base);
  float4* kd = (float4*)(k + base);
  float4* vd = (float4*)(v + base);
#pragma unroll
  for (int i4 = 0; i4 < 4; ++i4) {
    qd[i4] = make_float4(aq[i4*4], aq[i4*4+1], aq[i4*4+2], aq[i4*4+3]);
    kd[i4] = make_float4(ak[i4*4], ak[i4*4+1], ak[i4*4+2], ak[i4*4+3]);
    vd[i4] = make_float4(av[i4*4], av[i4*4+1], av[i4*4+2], av[i4*4+3]);
  }
}

// ---------------- 2x2 avg pool q,k,v -> qg,kg,vg ----------------
__global__ __launch_bounds__(256) void k_pool(
    const float* __restrict__ q, const float* __restrict__ k, const float* __restrict__ v,
    float* __restrict__ qg, float* __restrict__ kg, float* __restrict__ vg) {
  int idx = blockIdx.x * 256 + threadIdx.x;
  if (idx >= B_ * C_ * NG_) return;
  int bc = idx / NG_;
  int pos = idx - bc * NG_;
  int yy = pos / TG_, xx = pos - yy * TG_;
  size_t src = (size_t)bc * HW_ + (size_t)(2 * yy) * S_ + 2 * xx;
  qg[idx] = 0.25f * (q[src] + q[src+1] + q[src+S_] + q[src+S_+1]);
  kg[idx] = 0.25f * (k[src] + k[src+1] + k[src+S_] + k[src+S_+1]);
  vg[idx] = 0.25f * (v[src] + v[src+1] + v[src+S_] + v[src+S_+1]);
}

// ---------------- patch QK^T (split-K, atomic accumulate) ----------------
// S[i][j] = sum_m qf[m,i]*kf[m,j]; grid = B * 4(i-split) * 16(k-split)
__global__ __launch_bounds__(256) void k_pqk(const float* __restrict__ q,
                                             const float* __restrict__ k,
                                             float* __restrict__ sp) {
  int bid = blockIdx.x;
  int b = bid >> 6;
  int isplit = (bid >> 4) & 3;
  int ksp = bid & 15;
  int i0 = isplit * 49;
  int m0 = ksp * 256;
  const float* qb = q + (size_t)b * C_ * HW_;
  const float* kb = k + (size_t)b * C_ * HW_;
  __shared__ float qs[16 * 49];
  __shared__ float kss[16 * PA_];
  int tid = threadIdx.x;
  int ti = tid / 28;      // 0..6 (for tid < 196)
  int tj = tid - ti * 28; // 0..27
  bool active = tid < PA_;
  float acc[49];
#pragma unroll
  for (int t = 0; t < 49; ++t) acc[t] = 0.f;
  for (int mt = 0; mt < 256; mt += 16) {
    for (int idx = tid; idx < 16 * 49; idx += 256) {
      int mm = idx / 49, ii = idx - mm * 49;
      qs[idx] = qb[(size_t)(m0 + mt + mm) * PA_ + i0 + ii];
    }
    for (int idx = tid; idx < 16 * PA_; idx += 256) {
      int mm = idx / PA_, jj = idx - mm * PA_;
      kss[idx] = kb[(size_t)(m0 + mt + mm) * PA_ + jj];
    }
    __syncthreads();
    if (active) {
#pragma unroll 4
      for (int mm = 0; mm < 16; ++mm) {
        float qr[7], kr[7];
#pragma unroll
        for (int t = 0; t < 7; ++t) qr[t] = qs[mm * 49 + ti * 7 + t];
#pragma unroll
        for (int t = 0; t < 7; ++t) kr[t] = kss[mm * PA_ + tj * 7 + t];
#pragma unroll
        for (int a = 0; a < 7; ++a)
#pragma unroll
          for (int bb = 0; bb < 7; ++bb)
            acc[a * 7 + bb] += qr[a] * kr[bb];
      }
    }
    __syncthreads();
  }
  if (active) {
    float* srow = sp + (size_t)b * PA_ * PA_;
    const float sc = 1.0f / 64.0f;   // (C*SHN)^-0.5 = 4096^-0.5
    for (int a = 0; a < 7; ++a)
      for (int bb = 0; bb < 7; ++bb)
        atomicAdd(&srow[(size_t)(i0 + ti * 7 + a) * PA_ + tj * 7 + bb], acc[a * 7 + bb] * sc);
  }
}

// ---------------- patch softmax (row) -> transposed W^T[b][j][i] ----------------
__global__ __launch_bounds__(64) void k_psoftmax(const float* __restrict__ sp,
                                                 float* __restrict__ wt) {
  int row = blockIdx.x;            // b*196 + i
  int b = row / PA_, i = row - b * PA_;
  const float* srow = sp + (size_t)row * PA_;
  int lane = threadIdx.x;
  float v[4];
  float mx = -1e30f;
#pragma unroll
  for (int t = 0; t < 4; ++t) {
    int j = lane + t * 64;
    v[t] = (j < PA_) ? srow[j] : -1e30f;
    mx = fmaxf(mx, v[t]);
  }
  for (int o = 32; o > 0; o >>= 1) mx = fmaxf(mx, __shfl_xor(mx, o));
  float sum = 0.f;
#pragma unroll
  for (int t = 0; t < 4; ++t) { v[t] = __expf(v[t] - mx); sum += (lane + t * 64 < PA_) ? v[t] : 0.f; }
  for (int o = 32; o > 0; o >>= 1) sum += __shfl_xor(sum, o);
  float inv = 1.0f / sum;
  float* wb = wt + (size_t)b * PA_ * PApad_;
#pragma unroll
  for (int t = 0; t < 4; ++t) {
    int j = lane + t * 64;
    if (j < PA_) wb[(size_t)j * PApad_ + i] = v[t] * inv;
  }
}

// ---------------- patch AV: h[m][i] = sum_j vf[m][j] * WT[j][i] ----------------
__global__ __launch_bounds__(256) void k_pav(const float* __restrict__ v,
                                             const float* __restrict__ wt,
                                             float* __restrict__ hp) {
  int b = blockIdx.x >> 6;
  int mt = blockIdx.x & 63;
  int m0 = mt * 64;
  const float* vb = v + (size_t)b * C_ * HW_;
  const float* wb = wt + (size_t)b * PA_ * PApad_;
  float* hb = hp + (size_t)b * C_ * HW_;
  __shared__ float vt[64 * 17];
  __shared__ float wsh[16 * PApad_];
  int tid = threadIdx.x;
  int m = tid & 63, ih = tid >> 6;
  int i0 = ih * 52;
  float acc[52];
#pragma unroll
  for (int t = 0; t < 52; ++t) acc[t] = 0.f;
  for (int j0 = 0; j0 < PA_; j0 += 16) {
    for (int idx = tid; idx < 1024; idx += 256) {
      int mm = idx >> 4, jj = idx & 15;
      int j = j0 + jj;
      vt[mm * 17 + jj] = (j < PA_) ? vb[(size_t)(m0 + mm) * PA_ + j] : 0.f;
    }
    for (int idx = tid; idx < 16 * PApad_; idx += 256) {
      int jj = idx / PApad_, ii = idx - jj * PApad_;
      int j = j0 + jj;
      wsh[idx] = (j < PA_) ? wb[(size_t)j * PApad_ + ii] : 0.f;
    }
    __syncthreads();
#pragma unroll 2
    for (int jj = 0; jj < 16; ++jj) {
      float vv = vt[m * 17 + jj];
      const float4* wrow = (const float4*)(wsh + jj * PApad_ + i0);
#pragma unroll
      for (int t4 = 0; t4 < 13; ++t4) {
        float4 w4 = wrow[t4];
        acc[t4*4+0] += vv * w4.x;
        acc[t4*4+1] += vv * w4.y;
        acc[t4*4+2] += vv * w4.z;
        acc[t4*4+3] += vv * w4.w;
      }
    }
    __syncthreads();
  }
  size_t ob = (size_t)(m0 + m) * PA_ + i0;
  int ilim4 = (PA_ - i0) / 4;       // 13,13,13,10
  float4* hv = (float4*)(hb + ob);
#pragma unroll
  for (int t4 = 0; t4 < 13; ++t4)
    if (t4 < ilim4)
      hv[t4] = make_float4(acc[t4*4], acc[t4*4+1], acc[t4*4+2], acc[t4*4+3]);
}

// ---------------- global attention, flash-style ----------------
// grid = B * 49 (64-query tiles); seq 3136, dim 64
__global__ __launch_bounds__(256) void k_gattn(const float* __restrict__ qg,
                                               const float* __restrict__ kg,
                                               const float* __restrict__ vg,
                                               float* __restrict__ hg) {
  int b = blockIdx.x / 49;
  int it = blockIdx.x - b * 49;
  int i0 = it * 64;
  const float* qb = qg + (size_t)b * C_ * NG_;
  const float* kb = kg + (size_t)b * C_ * NG_;
  const float* vb = vg + (size_t)b * C_ * NG_;
  __shared__ float qs[64 * 64];   // [c][i]
  __shared__ float ks[64 * 32];   // [c][j]
  __shared__ float vs[64 * 33];   // [c][j] padded
  __shared__ float ps[64 * 33];   // [i][j] padded
  __shared__ float m_l[64], l_l[64], rf[64];
  int tid = threadIdx.x;
  for (int idx = tid; idx < 4096; idx += 256) {
    int c = idx >> 6, il = idx & 63;
    qs[idx] = qb[(size_t)c * NG_ + i0 + il];
  }
  if (tid < 64) { m_l[tid] = -1e30f; l_l[tid] = 0.f; rf[tid] = 0.f; }
  int si = tid >> 2;           // S-phase row
  int sj = tid & 3;            // S-phase j-group (8 each)
  int oc = tid & 63;           // O-phase channel
  int oi0 = (tid >> 6) * 16;   // O-phase i-range
  float acc[16];
#pragma unroll
  for (int t = 0; t < 16; ++t) acc[t] = 0.f;
  __syncthreads();
  for (int j0 = 0; j0 < NG_; j0 += 32) {
    for (int idx = tid; idx < 2048; idx += 256) {
      int c = idx >> 5, jl = idx & 31;
      float kvv = kb[(size_t)c * NG_ + j0 + jl];
      float vvv = vb[(size_t)c * NG_ + j0 + jl];
      ks[idx] = kvv;
      vs[c * 33 + jl] = vvv;
    }
    __syncthreads();
    float s[8];
#pragma unroll
    for (int t = 0; t < 8; ++t) s[t] = 0.f;
    for (int c = 0; c < 64; ++c) {
      float qv = qs[c * 64 + si];
#pragma unroll
      for (int t = 0; t < 8; ++t) s[t] += qv * ks[c * 32 + sj * 8 + t];
    }
    float pmax = -1e30f;
#pragma unroll
    for (int t = 0; t < 8; ++t) { s[t] *= 0.125f; pmax = fmaxf(pmax, s[t]); }
    pmax = fmaxf(pmax, __shfl_xor(pmax, 1));
    pmax = fmaxf(pmax, __shfl_xor(pmax, 2));
    float mold = m_l[si];
    float mnew = fmaxf(mold, pmax);
    float psum = 0.f;
#pragma unroll
    for (int t = 0; t < 8; ++t) { s[t] = __expf(s[t] - mnew); psum += s[t]; }
    psum += __shfl_xor(psum, 1);
    psum += __shfl_xor(psum, 2);
    float r = __expf(mold - mnew);
    if (sj == 0) {
      m_l[si] = mnew;
      l_l[si] = r * l_l[si] + psum;
      rf[si] = r;
    }
#pragma unroll
    for (int t = 0; t < 8; ++t) ps[si * 33 + sj * 8 + t] = s[t];
    __syncthreads();
#pragma unroll
    for (int t = 0; t < 16; ++t) acc[t] *= rf[oi0 + t];
    for (int jl = 0; jl < 32; ++jl) {
      float vv = vs[oc * 33 + jl];
#pragma unroll
      for (int t = 0; t < 16; ++t) acc[t] += vv * ps[(oi0 + t) * 33 + jl];
    }
    __syncthreads();
  }
  float* hb = hg + (size_t)b * C_ * NG_;
  size_t ob = (size_t)oc * NG_ + i0 + oi0;
  float4* hv = (float4*)(hb + ob);
#pragma unroll
  for (int t4 = 0; t4 < 4; ++t4) {
    float inv0 = 1.0f / l_l[oi0 + t4*4];
    float inv1 = 1.0f / l_l[oi0 + t4*4+1];
    float inv2 = 1.0f / l_l[oi0 + t4*4+2];
    float inv3 = 1.0f / l_l[oi0 + t4*4+3];
    hv[t4] = make_float4(acc[t4*4]*inv0, acc[t4*4+1]*inv1, acc[t4*4+2]*inv2, acc[t4*4+3]*inv3);
  }
}

// ---------------- final: bilinear upsample + mix + proj conv + residual ----------------
__global__ __launch_bounds__(256) void k_final(const float* __restrict__ xin,
                                               const float* __restrict__ hp,
                                               const float* __restrict__ hg,
                                               const float* __restrict__ wpT,
                                               float* __restrict__ out) {
  int b = blockIdx.x / S_, y = blockIdx.x - (blockIdx.x / S_) * S_;
  __shared__ float hmix[64 * 112];
  __shared__ float wps[4096];
  int tid = threadIdx.x;
  for (int idx = tid; idx < 4096; idx += 256) wps[idx] = wpT[idx];
  int th = y >> 1, r = y & 1;
  int y0 = r ? th : (th > 0 ? th - 1 : 0);
  int y1 = r ? (th < TG_ - 1 ? th + 1 : TG_ - 1) : th;
  float wy0 = r ? 0.75f : 0.25f;
  float wy1 = 1.0f - wy0;
  const float* hgb = hg + (size_t)b * C_ * NG_;
  const float* hpb = hp + (size_t)b * C_ * HW_;
  for (int idx = tid; idx < 64 * 112; idx += 256) {
    int c = idx / S_, xx = idx - c * S_;
    int u = xx >> 1, sx = xx & 1;
    int x0 = sx ? u : (u > 0 ? u - 1 : 0);
    int x1 = sx ? (u < TG_ - 1 ? u + 1 : TG_ - 1) : u;
    float wx0 = sx ? 0.75f : 0.25f;
    float wx1 = 1.0f - wx0;
    const float* g = hgb + (size_t)c * NG_;
    float up = wy0 * (wx0 * g[y0 * TG_ + x0] + wx1 * g[y0 * TG_ + x1])
             + wy1 * (wx0 * g[y1 * TG_ + x0] + wx1 * g[y1 * TG_ + x1]);
    hmix[idx] = 0.75f * hpb[(size_t)c * HW_ + (size_t)y * S_ + xx] + 0.25f * up;
  }
  __syncthreads();
  int o = tid & 63, gq = tid >> 6;
  float acc[28];
#pragma unroll
  for (int t = 0; t < 28; ++t) acc[t] = 0.f;
  for (int c = 0; c < 64; ++c) {
    float wv = wps[c * 64 + o];
    const float4* hrow = (const float4*)(hmix + c * S_ + gq * 28);
#pragma unroll
    for (int t4 = 0; t4 < 7; ++t4) {
      float4 h4 = hrow[t4];
      acc[t4*4+0] += wv * h4.x; acc[t4*4+1] += wv * h4.y;
      acc[t4*4+2] += wv * h4.z; acc[t4*4+3] += wv * h4.w;
    }
  }
  size_t ob = ((size_t)(b * 64 + o)) * HW_ + (size_t)y * S_ + gq * 28;
  const float4* xr = (const float4*)(xin + ob);
  float4* od = (float4*)(out + ob);
#pragma unroll
  for (int t4 = 0; t4 < 7; ++t4) {
    float4 xv = xr[t4];
    od[t4] = make_float4(xv.x + acc[t4*4], xv.y + acc[t4*4+1],
                         xv.z + acc[t4*4+2], xv.w + acc[t4*4+3]);
  }
}

extern "C" void kernel_launch(void* const* d_in, const int* in_sizes, int n_in,
                              void* d_out, int out_size, void* d_ws, size_t ws_size,
                              hipStream_t stream) {
  (void)in_sizes; (void)n_in; (void)out_size; (void)ws_size;
  const float* x   = (const float*)d_in[0];
  const float* gnw = (const float*)d_in[1];
  const float* gnb = (const float*)d_in[2];
  const float* wq  = (const float*)d_in[3];
  const float* bq  = (const float*)d_in[4];
  const float* wk  = (const float*)d_in[5];
  const float* bk  = (const float*)d_in[6];
  const float* wv  = (const float*)d_in[7];
  const float* bv  = (const float*)d_in[8];
  const float* wp  = (const float*)d_in[9];
  float* out = (float*)d_out;
  float* ws  = (float*)d_ws;

  // zero stats + patch logit accumulator (0xAA-poisoned otherwise)
  hipMemsetAsync(d_ws, 0, OFF_WQT * sizeof(float), stream);

  k_wtrans<<<16, 256, 0, stream>>>(wq, wk, wv, wp,
                                   ws + OFF_WQT, ws + OFF_WKT, ws + OFF_WVT, ws + OFF_WPT);
  k_gnstats<<<B_ * C_, 256, 0, stream>>>(x, ws + OFF_STATS);
  k_qkv<<<B_ * PA_, 256, 0, stream>>>(x, ws + OFF_STATS, gnw, gnb,
                                      ws + OFF_WQT, ws + OFF_WKT, ws + OFF_WVT,
                                      bq, bk, bv,
                                      ws + OFF_Q, ws + OFF_K, ws + OFF_V);
  k_pool<<<(B_ * C_ * NG_ + 255) / 256, 256, 0, stream>>>(
      ws + OFF_Q, ws + OFF_K, ws + OFF_V, ws + OFF_QG, ws + OFF_KG, ws + OFF_VG);
  k_pqk<<<B_ * 64, 256, 0, stream>>>(ws + OFF_Q, ws + OFF_K, ws + OFF_SP);
  k_psoftmax<<<B_ * PA_, 64, 0, stream>>>(ws + OFF_SP, ws + OFF_WT);
  // HP aliases Q region, HG aliases K region (both dead after k_pqk)
  k_pav<<<B_ * 64, 256, 0, stream>>>(ws + OFF_V, ws + OFF_WT, ws + OFF_HP);
  k_gattn<<<B_ * 49, 256, 0, stream>>>(ws + OFF_QG, ws + OFF_KG, ws + OFF_VG, ws + OFF_HG);
  k_final<<<B_ * S_, 256, 0, stream>>>(x, ws + OFF_HP, ws + OFF_HG, ws + OFF_WPT, out);
}

// Round 7
// 1272.598 us; speedup vs baseline: 1.1034x; 1.1034x over previous
//
#include <hip/hip_runtime.h>
#include <hip/hip_bf16.h>

#define B_ 8
#define C_ 64
#define S_ 112
#define HW_ 12544      // 112*112
#define NG_ 3136       // 56*56
#define TG_ 56
#define PA_ 196        // 14*14
#define PApad_ 208     // padded pitch for W^T (multiple of 4 for float4)
#define EPS_ 1e-5f
// global-attn tiling
#define QT_ 32         // queries per block
#define NQT_ 98        // NG_/QT_
#define NCH_ 2         // KV split chunks
#define JCH_ 1568      // NG_/NCH_
#define JST_ 32        // j step per LDS stage
#define GST_SZ 2112    // per-state floats: m[32] l[32] O[64*32]

// ---------------- ws layout (floats) ----------------
// HP aliases Q (dead after k_pqk); HG aliases K (dead after k_pqk);
// GSTATE aliases V (dead after k_pav). Stream order:
//  pqk(Q,K) -> psoftmax -> pav(V->HP) -> gattn_part(QG,KG,VG->GST) -> gmerge(GST->HG) -> final(HP,HG)
static constexpr size_t OFF_STATS = 0;                               // 64
static constexpr size_t OFF_SP    = 64;                              // B*196*196 patch logits
static constexpr size_t OFF_WQT   = OFF_SP + (size_t)B_*PA_*PA_;
static constexpr size_t OFF_WKT   = OFF_WQT + 4096;
static constexpr size_t OFF_WVT   = OFF_WKT + 4096;
static constexpr size_t OFF_WPT   = OFF_WVT + 4096;
static constexpr size_t OFF_WT    = OFF_WPT + 4096;                  // B*196*208
static constexpr size_t OFF_Q     = OFF_WT + (size_t)B_*PA_*PApad_;
static constexpr size_t OFF_K     = OFF_Q + (size_t)B_*C_*HW_;
static constexpr size_t OFF_V     = OFF_K + (size_t)B_*C_*HW_;
static constexpr size_t OFF_QG    = OFF_V + (size_t)B_*C_*HW_;
static constexpr size_t OFF_KG    = OFF_QG + (size_t)B_*C_*NG_;
static constexpr size_t OFF_VG    = OFF_KG + (size_t)B_*C_*NG_;
static constexpr size_t OFF_HP    = OFF_Q;                           // alias
static constexpr size_t OFF_HG    = OFF_K;                           // alias
static constexpr size_t OFF_GST   = OFF_V;                           // alias: B*98*2*2112 = 13.2MB < 25.7MB

// ---------------- weight transpose ----------------
__global__ void k_wtrans(const float* __restrict__ wq, const float* __restrict__ wk,
                         const float* __restrict__ wv, const float* __restrict__ wp,
                         float* __restrict__ qT, float* __restrict__ kT,
                         float* __restrict__ vT, float* __restrict__ pT) {
  int idx = blockIdx.x * 256 + threadIdx.x;
  if (idx < 4096) {
    int o = idx >> 6, c = idx & 63;
    int t = c * 64 + o;
    qT[t] = wq[idx]; kT[t] = wk[idx]; vT[t] = wv[idx]; pT[t] = wp[idx];
  }
}

// ---------------- GroupNorm stats ----------------
__global__ __launch_bounds__(256) void k_gnstats(const float* __restrict__ x,
                                                 float* __restrict__ stats) {
  int blk = blockIdx.x;            // b*64 + c
  int b = blk >> 6;
  const float4* p = (const float4*)(x + (size_t)blk * HW_);
  float s = 0.f, s2 = 0.f;
  for (int t = threadIdx.x; t < HW_ / 4; t += 256) {
    float4 v = p[t];
    s  += v.x + v.y + v.z + v.w;
    s2 += v.x*v.x + v.y*v.y + v.z*v.z + v.w*v.w;
  }
  for (int o = 32; o > 0; o >>= 1) { s += __shfl_down(s, o); s2 += __shfl_down(s2, o); }
  __shared__ float ls[4], ls2[4];
  int wid = threadIdx.x >> 6, lane = threadIdx.x & 63;
  if (lane == 0) { ls[wid] = s; ls2[wid] = s2; }
  __syncthreads();
  if (threadIdx.x == 0) {
    float a = 0.f, a2 = 0.f;
    for (int w = 0; w < 4; ++w) { a += ls[w]; a2 += ls2[w]; }
    atomicAdd(&stats[b * 2], a);
    atomicAdd(&stats[b * 2 + 1], a2);
  }
}

// ---------------- fused GroupNorm + QKV conv1x1 ----------------
__global__ __launch_bounds__(256) void k_qkv(
    const float* __restrict__ x, const float* __restrict__ stats,
    const float* __restrict__ gnw, const float* __restrict__ gnb,
    const float* __restrict__ wqT, const float* __restrict__ wkT, const float* __restrict__ wvT,
    const float* __restrict__ bq, const float* __restrict__ bk, const float* __restrict__ bv,
    float* __restrict__ q, float* __restrict__ k, float* __restrict__ v) {
  __shared__ float wqs[4096], wks[4096], wvs[4096], xt[4096];
  int b = blockIdx.x / PA_, tile = blockIdx.x % PA_;
  int s0 = tile * 64;
  int tid = threadIdx.x;
  for (int idx = tid; idx < 4096; idx += 256) {
    wqs[idx] = wqT[idx]; wks[idx] = wkT[idx]; wvs[idx] = wvT[idx];
  }
  float n  = (float)(C_ * HW_);
  float mu = stats[2 * b] / n;
  float var = stats[2 * b + 1] / n - mu * mu;
  float rs = rsqrtf(var + EPS_);
  for (int idx = tid; idx < 4096; idx += 256) {
    int c = idx >> 6, p = idx & 63;
    float val = x[((size_t)(b * 64 + c)) * HW_ + s0 + p];
    xt[idx] = (val - mu) * rs * gnw[c] + gnb[c];
  }
  __syncthreads();
  int o = tid & 63, g = tid >> 6;
  float aq[16], ak[16], av[16];
  float bqv = bq[o], bkv = bk[o], bvv = bv[o];
#pragma unroll
  for (int i = 0; i < 16; ++i) { aq[i] = bqv; ak[i] = bkv; av[i] = bvv; }
  for (int c = 0; c < 64; ++c) {
    float wqv = wqs[c * 64 + o], wkv = wks[c * 64 + o], wvv = wvs[c * 64 + o];
    const float4* xr = (const float4*)(xt + c * 64 + g * 16);
#pragma unroll
    for (int i4 = 0; i4 < 4; ++i4) {
      float4 xv = xr[i4];
      aq[i4*4+0] += wqv*xv.x; aq[i4*4+1] += wqv*xv.y; aq[i4*4+2] += wqv*xv.z; aq[i4*4+3] += wqv*xv.w;
      ak[i4*4+0] += wkv*xv.x; ak[i4*4+1] += wkv*xv.y; ak[i4*4+2] += wkv*xv.z; ak[i4*4+3] += wkv*xv.w;
      av[i4*4+0] += wvv*xv.x; av[i4*4+1] += wvv*xv.y; av[i4*4+2] += wvv*xv.z; av[i4*4+3] += wvv*xv.w;
    }
  }
  size_t base = ((size_t)(b * 64 + o)) * HW_ + s0 + g * 16;
  float4* qd = (float4*)(q + base);
  float4* kd = (float4*)(k + base);
  float4* vd = (float4*)(v + base);
#pragma unroll
  for (int i4 = 0; i4 < 4; ++i4) {
    qd[i4] = make_float4(aq[i4*4], aq[i4*4+1], aq[i4*4+2], aq[i4*4+3]);
    kd[i4] = make_float4(ak[i4*4], ak[i4*4+1], ak[i4*4+2], ak[i4*4+3]);
    vd[i4] = make_float4(av[i4*4], av[i4*4+1], av[i4*4+2], av[i4*4+3]);
  }
}

// ---------------- 2x2 avg pool ----------------
__global__ __launch_bounds__(256) void k_pool(
    const float* __restrict__ q, const float* __restrict__ k, const float* __restrict__ v,
    float* __restrict__ qg, float* __restrict__ kg, float* __restrict__ vg) {
  int idx = blockIdx.x * 256 + threadIdx.x;
  if (idx >= B_ * C_ * NG_) return;
  int bc = idx / NG_;
  int pos = idx - bc * NG_;
  int yy = pos / TG_, xx = pos - yy * TG_;
  size_t src = (size_t)bc * HW_ + (size_t)(2 * yy) * S_ + 2 * xx;
  qg[idx] = 0.25f * (q[src] + q[src+1] + q[src+S_] + q[src+S_+1]);
  kg[idx] = 0.25f * (k[src] + k[src+1] + k[src+S_] + k[src+S_+1]);
  vg[idx] = 0.25f * (v[src] + v[src+1] + v[src+S_] + v[src+S_+1]);
}

// ---------------- patch QK^T (split-K, atomic accumulate) ----------------
__global__ __launch_bounds__(256) void k_pqk(const float* __restrict__ q,
                                             const float* __restrict__ k,
                                             float* __restrict__ sp) {
  int bid = blockIdx.x;
  int b = bid >> 6;
  int isplit = (bid >> 4) & 3;
  int ksp = bid & 15;
  int i0 = isplit * 49;
  int m0 = ksp * 256;
  const float* qb = q + (size_t)b * C_ * HW_;
  const float* kb = k + (size_t)b * C_ * HW_;
  __shared__ float qs[16 * 49];
  __shared__ float kss[16 * PA_];
  int tid = threadIdx.x;
  int ti = tid / 28;
  int tj = tid - ti * 28;
  bool active = tid < PA_;
  float acc[49];
#pragma unroll
  for (int t = 0; t < 49; ++t) acc[t] = 0.f;
  for (int mt = 0; mt < 256; mt += 16) {
    for (int idx = tid; idx < 16 * 49; idx += 256) {
      int mm = idx / 49, ii = idx - mm * 49;
      qs[idx] = qb[(size_t)(m0 + mt + mm) * PA_ + i0 + ii];
    }
    for (int idx = tid; idx < 16 * PA_; idx += 256) {
      int mm = idx / PA_, jj = idx - mm * PA_;
      kss[idx] = kb[(size_t)(m0 + mt + mm) * PA_ + jj];
    }
    __syncthreads();
    if (active) {
#pragma unroll 4
      for (int mm = 0; mm < 16; ++mm) {
        float qr[7], kr[7];
#pragma unroll
        for (int t = 0; t < 7; ++t) qr[t] = qs[mm * 49 + ti * 7 + t];
#pragma unroll
        for (int t = 0; t < 7; ++t) kr[t] = kss[mm * PA_ + tj * 7 + t];
#pragma unroll
        for (int a = 0; a < 7; ++a)
#pragma unroll
          for (int bb = 0; bb < 7; ++bb)
            acc[a * 7 + bb] += qr[a] * kr[bb];
      }
    }
    __syncthreads();
  }
  if (active) {
    float* srow = sp + (size_t)b * PA_ * PA_;
    const float sc = 1.0f / 64.0f;
    for (int a = 0; a < 7; ++a)
      for (int bb = 0; bb < 7; ++bb)
        atomicAdd(&srow[(size_t)(i0 + ti * 7 + a) * PA_ + tj * 7 + bb], acc[a * 7 + bb] * sc);
  }
}

// ---------------- patch softmax -> transposed W^T ----------------
__global__ __launch_bounds__(64) void k_psoftmax(const float* __restrict__ sp,
                                                 float* __restrict__ wt) {
  int row = blockIdx.x;
  int b = row / PA_, i = row - b * PA_;
  const float* srow = sp + (size_t)row * PA_;
  int lane = threadIdx.x;
  float v[4];
  float mx = -1e30f;
#pragma unroll
  for (int t = 0; t < 4; ++t) {
    int j = lane + t * 64;
    v[t] = (j < PA_) ? srow[j] : -1e30f;
    mx = fmaxf(mx, v[t]);
  }
  for (int o = 32; o > 0; o >>= 1) mx = fmaxf(mx, __shfl_xor(mx, o));
  float sum = 0.f;
#pragma unroll
  for (int t = 0; t < 4; ++t) { v[t] = __expf(v[t] - mx); sum += (lane + t * 64 < PA_) ? v[t] : 0.f; }
  for (int o = 32; o > 0; o >>= 1) sum += __shfl_xor(sum, o);
  float inv = 1.0f / sum;
  float* wb = wt + (size_t)b * PA_ * PApad_;
#pragma unroll
  for (int t = 0; t < 4; ++t) {
    int j = lane + t * 64;
    if (j < PA_) wb[(size_t)j * PApad_ + i] = v[t] * inv;
  }
}

// ---------------- patch AV ----------------
__global__ __launch_bounds__(256) void k_pav(const float* __restrict__ v,
                                             const float* __restrict__ wt,
                                             float* __restrict__ hp) {
  int b = blockIdx.x >> 6;
  int mt = blockIdx.x & 63;
  int m0 = mt * 64;
  const float* vb = v + (size_t)b * C_ * HW_;
  const float* wb = wt + (size_t)b * PA_ * PApad_;
  float* hb = hp + (size_t)b * C_ * HW_;
  __shared__ float vt[64 * 17];
  __shared__ float wsh[16 * PApad_];
  int tid = threadIdx.x;
  int m = tid & 63, ih = tid >> 6;
  int i0 = ih * 52;
  float acc[52];
#pragma unroll
  for (int t = 0; t < 52; ++t) acc[t] = 0.f;
  for (int j0 = 0; j0 < PA_; j0 += 16) {
    for (int idx = tid; idx < 1024; idx += 256) {
      int mm = idx >> 4, jj = idx & 15;
      int j = j0 + jj;
      vt[mm * 17 + jj] = (j < PA_) ? vb[(size_t)(m0 + mm) * PA_ + j] : 0.f;
    }
    for (int idx = tid; idx < 16 * PApad_; idx += 256) {
      int jj = idx / PApad_, ii = idx - jj * PApad_;
      int j = j0 + jj;
      wsh[idx] = (j < PA_) ? wb[(size_t)j * PApad_ + ii] : 0.f;
    }
    __syncthreads();
#pragma unroll 2
    for (int jj = 0; jj < 16; ++jj) {
      float vv = vt[m * 17 + jj];
      const float4* wrow = (const float4*)(wsh + jj * PApad_ + i0);
#pragma unroll
      for (int t4 = 0; t4 < 13; ++t4) {
        float4 w4 = wrow[t4];
        acc[t4*4+0] += vv * w4.x;
        acc[t4*4+1] += vv * w4.y;
        acc[t4*4+2] += vv * w4.z;
        acc[t4*4+3] += vv * w4.w;
      }
    }
    __syncthreads();
  }
  size_t ob = (size_t)(m0 + m) * PA_ + i0;
  int ilim4 = (PA_ - i0) / 4;
  float4* hv = (float4*)(hb + ob);
#pragma unroll
  for (int t4 = 0; t4 < 13; ++t4)
    if (t4 < ilim4)
      hv[t4] = make_float4(acc[t4*4], acc[t4*4+1], acc[t4*4+2], acc[t4*4+3]);
}

// ---------------- global attention, flash split-KV partials ----------------
// grid = B * NQT * NCH; each block: 32 queries, scans NG/2 keys, emits (m,l,O) state.
// LDS 28.75KB -> 5 blocks/CU cap (was 42.5KB/392 blocks -> 15.7% occupancy).
__global__ __launch_bounds__(256) void k_gattn_part(const float* __restrict__ qg,
                                                    const float* __restrict__ kg,
                                                    const float* __restrict__ vg,
                                                    float* __restrict__ gst) {
  int bid = blockIdx.x;
  int ch = bid & (NCH_ - 1);
  int qt = (bid >> 1) % NQT_;
  int b  = bid / (NCH_ * NQT_);
  int i0 = qt * QT_;
  int jbeg = ch * JCH_;
  const float* qb = qg + (size_t)b * C_ * NG_;
  const float* kb = kg + (size_t)b * C_ * NG_;
  const float* vb = vg + (size_t)b * C_ * NG_;
  __shared__ float qs[64 * QT_];    // [c][i]
  __shared__ float ks[64 * JST_];   // [c][j]
  __shared__ float vs[64 * 33];     // [c][j] padded
  __shared__ float ps[QT_ * 33];    // [i][j] padded
  __shared__ float m_l[QT_], l_l[QT_], rf[QT_];
  int tid = threadIdx.x;
  for (int idx = tid; idx < 64 * QT_; idx += 256) {
    int c = idx >> 5, il = idx & 31;
    qs[idx] = qb[(size_t)c * NG_ + i0 + il];
  }
  if (tid < QT_) { m_l[tid] = -1e30f; l_l[tid] = 0.f; rf[tid] = 0.f; }
  int si = tid >> 3;           // S-phase row 0..31 (8 lanes each, within one wave)
  int sj = tid & 7;            // j-group of 4
  int oc = tid & 63;           // O-phase channel
  int oi0 = (tid >> 6) * 8;    // O-phase i-range
  float acc[8];
#pragma unroll
  for (int t = 0; t < 8; ++t) acc[t] = 0.f;
  __syncthreads();
  for (int j0 = jbeg; j0 < jbeg + JCH_; j0 += JST_) {
    for (int idx = tid; idx < 2048; idx += 256) {
      int c = idx >> 5, jl = idx & 31;
      ks[idx] = kb[(size_t)c * NG_ + j0 + jl];
      vs[c * 33 + jl] = vb[(size_t)c * NG_ + j0 + jl];
    }
    __syncthreads();
    float s[4] = {0.f, 0.f, 0.f, 0.f};
    for (int c = 0; c < 64; ++c) {
      float qv = qs[c * QT_ + si];
#pragma unroll
      for (int t = 0; t < 4; ++t) s[t] += qv * ks[c * JST_ + sj * 4 + t];
    }
    float pmax = -1e30f;
#pragma unroll
    for (int t = 0; t < 4; ++t) { s[t] *= 0.125f; pmax = fmaxf(pmax, s[t]); }
    pmax = fmaxf(pmax, __shfl_xor(pmax, 1));
    pmax = fmaxf(pmax, __shfl_xor(pmax, 2));
    pmax = fmaxf(pmax, __shfl_xor(pmax, 4));
    float mold = m_l[si];
    float mnew = fmaxf(mold, pmax);
    float psum = 0.f;
#pragma unroll
    for (int t = 0; t < 4; ++t) { s[t] = __expf(s[t] - mnew); psum += s[t]; }
    psum += __shfl_xor(psum, 1);
    psum += __shfl_xor(psum, 2);
    psum += __shfl_xor(psum, 4);
    float r = __expf(mold - mnew);
    if (sj == 0) {
      m_l[si] = mnew;
      l_l[si] = r * l_l[si] + psum;
      rf[si] = r;
    }
#pragma unroll
    for (int t = 0; t < 4; ++t) ps[si * 33 + sj * 4 + t] = s[t];
    __syncthreads();
#pragma unroll
    for (int t = 0; t < 8; ++t) acc[t] *= rf[oi0 + t];
    for (int jl = 0; jl < JST_; ++jl) {
      float vv = vs[oc * 33 + jl];
#pragma unroll
      for (int t = 0; t < 8; ++t) acc[t] += vv * ps[(oi0 + t) * 33 + jl];
    }
    __syncthreads();
  }
  // emit state: [m[32] | l[32] | O[64c][32i]]
  float* st = gst + (size_t)bid * GST_SZ;
  if (tid < QT_) { st[tid] = m_l[tid]; st[QT_ + tid] = l_l[tid]; }
#pragma unroll
  for (int t = 0; t < 8; ++t) st[2 * QT_ + oc * QT_ + oi0 + t] = acc[t];
}

// ---------------- exact merge of the 2 KV-chunk states ----------------
__global__ __launch_bounds__(256) void k_gmerge(const float* __restrict__ gst,
                                                float* __restrict__ hg) {
  int bid = blockIdx.x;            // b*NQT + qt
  int b = bid / NQT_, qt = bid - b * NQT_;
  const float* s0 = gst + (size_t)(bid * NCH_ + 0) * GST_SZ;
  const float* s1 = gst + (size_t)(bid * NCH_ + 1) * GST_SZ;
  __shared__ float w0[QT_], w1[QT_];
  int tid = threadIdx.x;
  if (tid < QT_) {
    float m0 = s0[tid], m1 = s1[tid];
    float l0 = s0[QT_ + tid], l1 = s1[QT_ + tid];
    float m = fmaxf(m0, m1);
    float e0 = __expf(m0 - m), e1 = __expf(m1 - m);
    float linv = 1.0f / (l0 * e0 + l1 * e1);
    w0[tid] = e0 * linv; w1[tid] = e1 * linv;
  }
  __syncthreads();
  int i0 = qt * QT_;
  float* hb = hg + (size_t)b * C_ * NG_;
  for (int idx = tid; idx < 64 * QT_; idx += 256) {
    int c = idx >> 5, i = idx & 31;
    hb[(size_t)c * NG_ + i0 + i] = s0[2 * QT_ + idx] * w0[i] + s1[2 * QT_ + idx] * w1[i];
  }
}

// ---------------- final: bilinear upsample + mix + proj conv + residual ----------------
__global__ __launch_bounds__(256) void k_final(const float* __restrict__ xin,
                                               const float* __restrict__ hp,
                                               const float* __restrict__ hg,
                                               const float* __restrict__ wpT,
                                               float* __restrict__ out) {
  int b = blockIdx.x / S_, y = blockIdx.x - (blockIdx.x / S_) * S_;
  __shared__ float hmix[64 * 112];
  __shared__ float wps[4096];
  int tid = threadIdx.x;
  for (int idx = tid; idx < 4096; idx += 256) wps[idx] = wpT[idx];
  int th = y >> 1, r = y & 1;
  int y0 = r ? th : (th > 0 ? th - 1 : 0);
  int y1 = r ? (th < TG_ - 1 ? th + 1 : TG_ - 1) : th;
  float wy0 = r ? 0.75f : 0.25f;
  float wy1 = 1.0f - wy0;
  const float* hgb = hg + (size_t)b * C_ * NG_;
  const float* hpb = hp + (size_t)b * C_ * HW_;
  for (int idx = tid; idx < 64 * 112; idx += 256) {
    int c = idx / S_, xx = idx - c * S_;
    int u = xx >> 1, sx = xx & 1;
    int x0 = sx ? u : (u > 0 ? u - 1 : 0);
    int x1 = sx ? (u < TG_ - 1 ? u + 1 : TG_ - 1) : u;
    float wx0 = sx ? 0.75f : 0.25f;
    float wx1 = 1.0f - wx0;
    const float* g = hgb + (size_t)c * NG_;
    float up = wy0 * (wx0 * g[y0 * TG_ + x0] + wx1 * g[y0 * TG_ + x1])
             + wy1 * (wx0 * g[y1 * TG_ + x0] + wx1 * g[y1 * TG_ + x1]);
    hmix[idx] = 0.75f * hpb[(size_t)c * HW_ + (size_t)y * S_ + xx] + 0.25f * up;
  }
  __syncthreads();
  int o = tid & 63, gq = tid >> 6;
  float acc[28];
#pragma unroll
  for (int t = 0; t < 28; ++t) acc[t] = 0.f;
  for (int c = 0; c < 64; ++c) {
    float wv = wps[c * 64 + o];
    const float4* hrow = (const float4*)(hmix + c * S_ + gq * 28);
#pragma unroll
    for (int t4 = 0; t4 < 7; ++t4) {
      float4 h4 = hrow[t4];
      acc[t4*4+0] += wv * h4.x; acc[t4*4+1] += wv * h4.y;
      acc[t4*4+2] += wv * h4.z; acc[t4*4+3] += wv * h4.w;
    }
  }
  size_t ob = ((size_t)(b * 64 + o)) * HW_ + (size_t)y * S_ + gq * 28;
  const float4* xr = (const float4*)(xin + ob);
  float4* od = (float4*)(out + ob);
#pragma unroll
  for (int t4 = 0; t4 < 7; ++t4) {
    float4 xv = xr[t4];
    od[t4] = make_float4(xv.x + acc[t4*4], xv.y + acc[t4*4+1],
                         xv.z + acc[t4*4+2], xv.w + acc[t4*4+3]);
  }
}

extern "C" void kernel_launch(void* const* d_in, const int* in_sizes, int n_in,
                              void* d_out, int out_size, void* d_ws, size_t ws_size,
                              hipStream_t stream) {
  (void)in_sizes; (void)n_in; (void)out_size; (void)ws_size;
  const float* x   = (const float*)d_in[0];
  const float* gnw = (const float*)d_in[1];
  const float* gnb = (const float*)d_in[2];
  const float* wq  = (const float*)d_in[3];
  const float* bq  = (const float*)d_in[4];
  const float* wk  = (const float*)d_in[5];
  const float* bk  = (const float*)d_in[6];
  const float* wv  = (const float*)d_in[7];
  const float* bv  = (const float*)d_in[8];
  const float* wp  = (const float*)d_in[9];
  float* out = (float*)d_out;
  float* ws  = (float*)d_ws;

  hipMemsetAsync(d_ws, 0, OFF_WQT * sizeof(float), stream);

  k_wtrans<<<16, 256, 0, stream>>>(wq, wk, wv, wp,
                                   ws + OFF_WQT, ws + OFF_WKT, ws + OFF_WVT, ws + OFF_WPT);
  k_gnstats<<<B_ * C_, 256, 0, stream>>>(x, ws + OFF_STATS);
  k_qkv<<<B_ * PA_, 256, 0, stream>>>(x, ws + OFF_STATS, gnw, gnb,
                                      ws + OFF_WQT, ws + OFF_WKT, ws + OFF_WVT,
                                      bq, bk, bv,
                                      ws + OFF_Q, ws + OFF_K, ws + OFF_V);
  k_pool<<<(B_ * C_ * NG_ + 255) / 256, 256, 0, stream>>>(
      ws + OFF_Q, ws + OFF_K, ws + OFF_V, ws + OFF_QG, ws + OFF_KG, ws + OFF_VG);
  k_pqk<<<B_ * 64, 256, 0, stream>>>(ws + OFF_Q, ws + OFF_K, ws + OFF_SP);
  k_psoftmax<<<B_ * PA_, 64, 0, stream>>>(ws + OFF_SP, ws + OFF_WT);
  // HP aliases Q, HG aliases K (dead after k_pqk); GST aliases V (dead after k_pav)
  k_pav<<<B_ * 64, 256, 0, stream>>>(ws + OFF_V, ws + OFF_WT, ws + OFF_HP);
  k_gattn_part<<<B_ * NQT_ * NCH_, 256, 0, stream>>>(ws + OFF_QG, ws + OFF_KG, ws + OFF_VG,
                                                     ws + OFF_GST);
  k_gmerge<<<B_ * NQT_, 256, 0, stream>>>(ws + OFF_GST, ws + OFF_HG);
  k_final<<<B_ * S_, 256, 0, stream>>>(x, ws + OFF_HP, ws + OFF_HG, ws + OFF_WPT, out);
}

// Round 8
// 863.685 us; speedup vs baseline: 1.6258x; 1.4735x over previous
//
#include <hip/hip_runtime.h>
#include <hip/hip_bf16.h>
#include <string.h>

#define B_ 8
#define C_ 64
#define S_ 112
#define HW_ 12544      // 112*112
#define NG_ 3136       // 56*56
#define TG_ 56
#define PA_ 196        // 14*14
#define PApad_ 208
#define EPS_ 1e-5f
// global-attn tiling
#define QT_ 32         // queries per block
#define NQT_ 98        // NG_/QT_
#define NCH_ 2         // KV split chunks
#define JCH_ 1568      // NG_/NCH_
#define NT_ 49         // KV tiles of 32 per chunk
#define GST_SZ 2112    // per-state floats: m[32] l[32] O[64*32]

typedef __attribute__((ext_vector_type(8))) short short8;
typedef __attribute__((ext_vector_type(4))) float f32x4;

// ---------------- ws layout (floats) ----------------
static constexpr size_t OFF_STATS = 0;
static constexpr size_t OFF_SP    = 64;
static constexpr size_t OFF_WQT   = OFF_SP + (size_t)B_*PA_*PA_;
static constexpr size_t OFF_WKT   = OFF_WQT + 4096;
static constexpr size_t OFF_WVT   = OFF_WKT + 4096;
static constexpr size_t OFF_WPT   = OFF_WVT + 4096;
static constexpr size_t OFF_WT    = OFF_WPT + 4096;
static constexpr size_t OFF_Q     = OFF_WT + (size_t)B_*PA_*PApad_;
static constexpr size_t OFF_K     = OFF_Q + (size_t)B_*C_*HW_;
static constexpr size_t OFF_V     = OFF_K + (size_t)B_*C_*HW_;
static constexpr size_t OFF_QG    = OFF_V + (size_t)B_*C_*HW_;
static constexpr size_t OFF_KG    = OFF_QG + (size_t)B_*C_*NG_;
static constexpr size_t OFF_VG    = OFF_KG + (size_t)B_*C_*NG_;
static constexpr size_t OFF_HP    = OFF_Q;                           // alias
static constexpr size_t OFF_HG    = OFF_K;                           // alias
static constexpr size_t OFF_GST   = OFF_V;                           // alias

__device__ __forceinline__ unsigned int pack_bf16(float a, float b) {
  __hip_bfloat16 ha = __float2bfloat16(a), hb = __float2bfloat16(b);
  unsigned short ua, ub;
  memcpy(&ua, &ha, 2); memcpy(&ub, &hb, 2);
  return (unsigned int)ua | ((unsigned int)ub << 16);
}

// ---------------- weight transpose ----------------
__global__ void k_wtrans(const float* __restrict__ wq, const float* __restrict__ wk,
                         const float* __restrict__ wv, const float* __restrict__ wp,
                         float* __restrict__ qT, float* __restrict__ kT,
                         float* __restrict__ vT, float* __restrict__ pT) {
  int idx = blockIdx.x * 256 + threadIdx.x;
  if (idx < 4096) {
    int o = idx >> 6, c = idx & 63;
    int t = c * 64 + o;
    qT[t] = wq[idx]; kT[t] = wk[idx]; vT[t] = wv[idx]; pT[t] = wp[idx];
  }
}

// ---------------- GroupNorm stats ----------------
__global__ __launch_bounds__(256) void k_gnstats(const float* __restrict__ x,
                                                 float* __restrict__ stats) {
  int blk = blockIdx.x;
  int b = blk >> 6;
  const float4* p = (const float4*)(x + (size_t)blk * HW_);
  float s = 0.f, s2 = 0.f;
  for (int t = threadIdx.x; t < HW_ / 4; t += 256) {
    float4 v = p[t];
    s  += v.x + v.y + v.z + v.w;
    s2 += v.x*v.x + v.y*v.y + v.z*v.z + v.w*v.w;
  }
  for (int o = 32; o > 0; o >>= 1) { s += __shfl_down(s, o); s2 += __shfl_down(s2, o); }
  __shared__ float ls[4], ls2[4];
  int wid = threadIdx.x >> 6, lane = threadIdx.x & 63;
  if (lane == 0) { ls[wid] = s; ls2[wid] = s2; }
  __syncthreads();
  if (threadIdx.x == 0) {
    float a = 0.f, a2 = 0.f;
    for (int w = 0; w < 4; ++w) { a += ls[w]; a2 += ls2[w]; }
    atomicAdd(&stats[b * 2], a);
    atomicAdd(&stats[b * 2 + 1], a2);
  }
}

// ---------------- fused GroupNorm + QKV conv1x1 ----------------
__global__ __launch_bounds__(256) void k_qkv(
    const float* __restrict__ x, const float* __restrict__ stats,
    const float* __restrict__ gnw, const float* __restrict__ gnb,
    const float* __restrict__ wqT, const float* __restrict__ wkT, const float* __restrict__ wvT,
    const float* __restrict__ bq, const float* __restrict__ bk, const float* __restrict__ bv,
    float* __restrict__ q, float* __restrict__ k, float* __restrict__ v) {
  __shared__ float wqs[4096], wks[4096], wvs[4096], xt[4096];
  int b = blockIdx.x / PA_, tile = blockIdx.x % PA_;
  int s0 = tile * 64;
  int tid = threadIdx.x;
  for (int idx = tid; idx < 4096; idx += 256) {
    wqs[idx] = wqT[idx]; wks[idx] = wkT[idx]; wvs[idx] = wvT[idx];
  }
  float n  = (float)(C_ * HW_);
  float mu = stats[2 * b] / n;
  float var = stats[2 * b + 1] / n - mu * mu;
  float rs = rsqrtf(var + EPS_);
  for (int idx = tid; idx < 4096; idx += 256) {
    int c = idx >> 6, p = idx & 63;
    float val = x[((size_t)(b * 64 + c)) * HW_ + s0 + p];
    xt[idx] = (val - mu) * rs * gnw[c] + gnb[c];
  }
  __syncthreads();
  int o = tid & 63, g = tid >> 6;
  float aq[16], ak[16], av[16];
  float bqv = bq[o], bkv = bk[o], bvv = bv[o];
#pragma unroll
  for (int i = 0; i < 16; ++i) { aq[i] = bqv; ak[i] = bkv; av[i] = bvv; }
  for (int c = 0; c < 64; ++c) {
    float wqv = wqs[c * 64 + o], wkv = wks[c * 64 + o], wvv = wvs[c * 64 + o];
    const float4* xr = (const float4*)(xt + c * 64 + g * 16);
#pragma unroll
    for (int i4 = 0; i4 < 4; ++i4) {
      float4 xv = xr[i4];
      aq[i4*4+0] += wqv*xv.x; aq[i4*4+1] += wqv*xv.y; aq[i4*4+2] += wqv*xv.z; aq[i4*4+3] += wqv*xv.w;
      ak[i4*4+0] += wkv*xv.x; ak[i4*4+1] += wkv*xv.y; ak[i4*4+2] += wkv*xv.z; ak[i4*4+3] += wkv*xv.w;
      av[i4*4+0] += wvv*xv.x; av[i4*4+1] += wvv*xv.y; av[i4*4+2] += wvv*xv.z; av[i4*4+3] += wvv*xv.w;
    }
  }
  size_t base = ((size_t)(b * 64 + o)) * HW_ + s0 + g * 16;
  float4* qd = (float4*)(q + base);
  float4* kd = (float4*)(k + base);
  float4* vd = (float4*)(v + base);
#pragma unroll
  for (int i4 = 0; i4 < 4; ++i4) {
    qd[i4] = make_float4(aq[i4*4], aq[i4*4+1], aq[i4*4+2], aq[i4*4+3]);
    kd[i4] = make_float4(ak[i4*4], ak[i4*4+1], ak[i4*4+2], ak[i4*4+3]);
    vd[i4] = make_float4(av[i4*4], av[i4*4+1], av[i4*4+2], av[i4*4+3]);
  }
}

// ---------------- 2x2 avg pool ----------------
__global__ __launch_bounds__(256) void k_pool(
    const float* __restrict__ q, const float* __restrict__ k, const float* __restrict__ v,
    float* __restrict__ qg, float* __restrict__ kg, float* __restrict__ vg) {
  int idx = blockIdx.x * 256 + threadIdx.x;
  if (idx >= B_ * C_ * NG_) return;
  int bc = idx / NG_;
  int pos = idx - bc * NG_;
  int yy = pos / TG_, xx = pos - yy * TG_;
  size_t src = (size_t)bc * HW_ + (size_t)(2 * yy) * S_ + 2 * xx;
  qg[idx] = 0.25f * (q[src] + q[src+1] + q[src+S_] + q[src+S_+1]);
  kg[idx] = 0.25f * (k[src] + k[src+1] + k[src+S_] + k[src+S_+1]);
  vg[idx] = 0.25f * (v[src] + v[src+1] + v[src+S_] + v[src+S_+1]);
}

// ---------------- patch QK^T (split-K, atomic accumulate) ----------------
__global__ __launch_bounds__(256) void k_pqk(const float* __restrict__ q,
                                             const float* __restrict__ k,
                                             float* __restrict__ sp) {
  int bid = blockIdx.x;
  int b = bid >> 6;
  int isplit = (bid >> 4) & 3;
  int ksp = bid & 15;
  int i0 = isplit * 49;
  int m0 = ksp * 256;
  const float* qb = q + (size_t)b * C_ * HW_;
  const float* kb = k + (size_t)b * C_ * HW_;
  __shared__ float qs[16 * 49];
  __shared__ float kss[16 * PA_];
  int tid = threadIdx.x;
  int ti = tid / 28;
  int tj = tid - ti * 28;
  bool active = tid < PA_;
  float acc[49];
#pragma unroll
  for (int t = 0; t < 49; ++t) acc[t] = 0.f;
  for (int mt = 0; mt < 256; mt += 16) {
    for (int idx = tid; idx < 16 * 49; idx += 256) {
      int mm = idx / 49, ii = idx - mm * 49;
      qs[idx] = qb[(size_t)(m0 + mt + mm) * PA_ + i0 + ii];
    }
    for (int idx = tid; idx < 16 * PA_; idx += 256) {
      int mm = idx / PA_, jj = idx - mm * PA_;
      kss[idx] = kb[(size_t)(m0 + mt + mm) * PA_ + jj];
    }
    __syncthreads();
    if (active) {
#pragma unroll 4
      for (int mm = 0; mm < 16; ++mm) {
        float qr[7], kr[7];
#pragma unroll
        for (int t = 0; t < 7; ++t) qr[t] = qs[mm * 49 + ti * 7 + t];
#pragma unroll
        for (int t = 0; t < 7; ++t) kr[t] = kss[mm * PA_ + tj * 7 + t];
#pragma unroll
        for (int a = 0; a < 7; ++a)
#pragma unroll
          for (int bb = 0; bb < 7; ++bb)
            acc[a * 7 + bb] += qr[a] * kr[bb];
      }
    }
    __syncthreads();
  }
  if (active) {
    float* srow = sp + (size_t)b * PA_ * PA_;
    const float sc = 1.0f / 64.0f;
    for (int a = 0; a < 7; ++a)
      for (int bb = 0; bb < 7; ++bb)
        atomicAdd(&srow[(size_t)(i0 + ti * 7 + a) * PA_ + tj * 7 + bb], acc[a * 7 + bb] * sc);
  }
}

// ---------------- patch softmax -> transposed W^T ----------------
__global__ __launch_bounds__(64) void k_psoftmax(const float* __restrict__ sp,
                                                 float* __restrict__ wt) {
  int row = blockIdx.x;
  int b = row / PA_, i = row - b * PA_;
  const float* srow = sp + (size_t)row * PA_;
  int lane = threadIdx.x;
  float v[4];
  float mx = -1e30f;
#pragma unroll
  for (int t = 0; t < 4; ++t) {
    int j = lane + t * 64;
    v[t] = (j < PA_) ? srow[j] : -1e30f;
    mx = fmaxf(mx, v[t]);
  }
  for (int o = 32; o > 0; o >>= 1) mx = fmaxf(mx, __shfl_xor(mx, o));
  float sum = 0.f;
#pragma unroll
  for (int t = 0; t < 4; ++t) { v[t] = __expf(v[t] - mx); sum += (lane + t * 64 < PA_) ? v[t] : 0.f; }
  for (int o = 32; o > 0; o >>= 1) sum += __shfl_xor(sum, o);
  float inv = 1.0f / sum;
  float* wb = wt + (size_t)b * PA_ * PApad_;
#pragma unroll
  for (int t = 0; t < 4; ++t) {
    int j = lane + t * 64;
    if (j < PA_) wb[(size_t)j * PApad_ + i] = v[t] * inv;
  }
}

// ---------------- patch AV ----------------
__global__ __launch_bounds__(256) void k_pav(const float* __restrict__ v,
                                             const float* __restrict__ wt,
                                             float* __restrict__ hp) {
  int b = blockIdx.x >> 6;
  int mt = blockIdx.x & 63;
  int m0 = mt * 64;
  const float* vb = v + (size_t)b * C_ * HW_;
  const float* wb = wt + (size_t)b * PA_ * PApad_;
  float* hb = hp + (size_t)b * C_ * HW_;
  __shared__ float vt[64 * 17];
  __shared__ float wsh[16 * PApad_];
  int tid = threadIdx.x;
  int m = tid & 63, ih = tid >> 6;
  int i0 = ih * 52;
  float acc[52];
#pragma unroll
  for (int t = 0; t < 52; ++t) acc[t] = 0.f;
  for (int j0 = 0; j0 < PA_; j0 += 16) {
    for (int idx = tid; idx < 1024; idx += 256) {
      int mm = idx >> 4, jj = idx & 15;
      int j = j0 + jj;
      vt[mm * 17 + jj] = (j < PA_) ? vb[(size_t)(m0 + mm) * PA_ + j] : 0.f;
    }
    for (int idx = tid; idx < 16 * PApad_; idx += 256) {
      int jj = idx / PApad_, ii = idx - jj * PApad_;
      int j = j0 + jj;
      wsh[idx] = (j < PA_) ? wb[(size_t)j * PApad_ + ii] : 0.f;
    }
    __syncthreads();
#pragma unroll 2
    for (int jj = 0; jj < 16; ++jj) {
      float vv = vt[m * 17 + jj];
      const float4* wrow = (const float4*)(wsh + jj * PApad_ + i0);
#pragma unroll
      for (int t4 = 0; t4 < 13; ++t4) {
        float4 w4 = wrow[t4];
        acc[t4*4+0] += vv * w4.x;
        acc[t4*4+1] += vv * w4.y;
        acc[t4*4+2] += vv * w4.z;
        acc[t4*4+3] += vv * w4.w;
      }
    }
    __syncthreads();
  }
  size_t ob = (size_t)(m0 + m) * PA_ + i0;
  int ilim4 = (PA_ - i0) / 4;
  float4* hv = (float4*)(hb + ob);
#pragma unroll
  for (int t4 = 0; t4 < 13; ++t4)
    if (t4 < ilim4)
      hv[t4] = make_float4(acc[t4*4], acc[t4*4+1], acc[t4*4+2], acc[t4*4+3]);
}

// ---------------- global attention, flash split-KV partials, bf16 MFMA ----------------
// grid = B*NQT*NCH; 32 queries/block, 1568 keys/chunk, KV tile 32.
// 4 waves: wave w = (it,jt) computes S tile [16i x 16j] via 2x mfma_16x16x32;
// PV: wave w owns c-rows [16w,16w+16), both i-halves: 2x mfma per tile.
// Flash state (m,l) exact fp32 in wave-0 registers; split-softmax merge per tile.
__global__ __launch_bounds__(256) void k_gattn_part(const float* __restrict__ qg,
                                                    const float* __restrict__ kg,
                                                    const float* __restrict__ vg,
                                                    float* __restrict__ gst) {
  int bid = blockIdx.x;
  int ch = bid & (NCH_ - 1);
  int qt = (bid >> 1) % NQT_;
  int b  = bid / (NCH_ * NQT_);
  int i0 = qt * QT_;
  int jbeg = ch * JCH_;
  const float* qb = qg + (size_t)b * C_ * NG_;
  const float* kb = kg + (size_t)b * C_ * NG_;
  const float* vb = vg + (size_t)b * C_ * NG_;

  // LDS: bf16 operand tiles. Row strides: 72 (Q/K: 64c+8 pad), 40 (V/P: 32+8 pad).
  __shared__ __align__(16) unsigned short qA[32 * 72];      // [i][c] A-frag layout
  __shared__ __align__(16) unsigned short kB[2][32 * 72];   // [j][c] B-frag layout
  __shared__ __align__(16) unsigned short vA[2][64 * 40];   // [c][j] A-frag layout
  __shared__ __align__(16) unsigned short pP[32 * 40];      // [i][j] B-frag layout
  __shared__ float mpart[2][QT_], spart[2][QT_];
  __shared__ float rf_s[QT_], efac_s[2][QT_], l_fin[QT_];

  int tid = threadIdx.x;
  int w = tid >> 6, ln = tid & 63;
  int it = w >> 1, jt = w & 1;
  int l15 = ln & 15, g = ln >> 4;

  // ---- stage Q (x0.125 folded; exact pow2 scale in bf16) ----
#pragma unroll
  for (int k2 = 0; k2 < 4; ++k2) {
    int idx = tid + k2 * 256;           // 0..1023 dword-packs
    int il = idx & 31, cp = idx >> 5;   // cp 0..31 -> c pair (2cp,2cp+1)
    float a = qb[(size_t)(2 * cp) * NG_ + i0 + il] * 0.125f;
    float bb = qb[(size_t)(2 * cp + 1) * NG_ + i0 + il] * 0.125f;
    *(unsigned int*)&qA[il * 72 + cp * 2] = pack_bf16(a, bb);
  }
  // ---- stage K/V tile 0 ----
  {
    int j0n = jbeg;
#pragma unroll
    for (int k2 = 0; k2 < 4; ++k2) {
      int idx = tid + k2 * 256;
      int jl = idx & 31, cp = idx >> 5;
      float a = kb[(size_t)(2 * cp) * NG_ + j0n + jl];
      float bb = kb[(size_t)(2 * cp + 1) * NG_ + j0n + jl];
      *(unsigned int*)&kB[0][jl * 72 + cp * 2] = pack_bf16(a, bb);
    }
#pragma unroll
    for (int k2 = 0; k2 < 4; ++k2) {
      int idx = tid + k2 * 256;
      int c = idx >> 4, jp = idx & 15;
      float2 vv = *(const float2*)&vb[(size_t)c * NG_ + j0n + 2 * jp];
      *(unsigned int*)&vA[0][c * 40 + jp * 2] = pack_bf16(vv.x, vv.y);
    }
  }
  f32x4 accO0 = {0.f, 0.f, 0.f, 0.f};
  f32x4 accO1 = {0.f, 0.f, 0.f, 0.f};
  float m_st = -1e30f, l_st = 0.f;   // wave0 lanes<32: per-row flash state
  __syncthreads();

  // hoisted A-frag addresses (constant over tiles)
  const unsigned short* qrow = &qA[(it * 16 + l15) * 72 + g * 8];

#pragma unroll 1
  for (int t = 0; t < NT_; ++t) {
    int cur = t & 1, nxt = cur ^ 1;
    // 1. issue global loads for tile t+1 (write to LDS later, after B2)
    float kf[8], vf[8];
    bool have = (t + 1 < NT_);
    if (have) {
      int j0n = jbeg + (t + 1) * 32;
#pragma unroll
      for (int k2 = 0; k2 < 4; ++k2) {
        int idx = tid + k2 * 256;
        int jl = idx & 31, cp = idx >> 5;
        kf[2 * k2]     = kb[(size_t)(2 * cp) * NG_ + j0n + jl];
        kf[2 * k2 + 1] = kb[(size_t)(2 * cp + 1) * NG_ + j0n + jl];
      }
#pragma unroll
      for (int k2 = 0; k2 < 4; ++k2) {
        int idx = tid + k2 * 256;
        int c = idx >> 4, jp = idx & 15;
        float2 vv = *(const float2*)&vb[(size_t)c * NG_ + j0n + 2 * jp];
        vf[2 * k2] = vv.x; vf[2 * k2 + 1] = vv.y;
      }
    }
    // 2. S = (Q^T K)*0.125 : two chained MFMAs over c-halves
    f32x4 s4 = {0.f, 0.f, 0.f, 0.f};
    {
      const unsigned short* krow = &kB[cur][(jt * 16 + l15) * 72 + g * 8];
      short8 a0 = *(const short8*)(qrow);
      short8 b0 = *(const short8*)(krow);
      s4 = __builtin_amdgcn_mfma_f32_16x16x32_bf16(a0, b0, s4, 0, 0, 0);
      short8 a1 = *(const short8*)(qrow + 32);
      short8 b1 = *(const short8*)(krow + 32);
      s4 = __builtin_amdgcn_mfma_f32_16x16x32_bf16(a1, b1, s4, 0, 0, 0);
    }
    // 3. per-jt partial softmax (local max/sum, exact merge later)
    float pmx[4], pex[4], psm[4];
#pragma unroll
    for (int r = 0; r < 4; ++r) {
      float m = s4[r];
      m = fmaxf(m, __shfl_xor(m, 1));
      m = fmaxf(m, __shfl_xor(m, 2));
      m = fmaxf(m, __shfl_xor(m, 4));
      m = fmaxf(m, __shfl_xor(m, 8));
      pmx[r] = m;
      pex[r] = __expf(s4[r] - m);
      float su = pex[r];
      su += __shfl_xor(su, 1);
      su += __shfl_xor(su, 2);
      su += __shfl_xor(su, 4);
      su += __shfl_xor(su, 8);
      psm[r] = su;
    }
    if (l15 == 0) {
#pragma unroll
      for (int r = 0; r < 4; ++r) {
        mpart[jt][it * 16 + 4 * g + r] = pmx[r];
        spart[jt][it * 16 + 4 * g + r] = psm[r];
      }
    }
    // 4. B2
    __syncthreads();
    // 5. LDS-write staged K/V; wave0 merges partials, updates flash state
    if (have) {
#pragma unroll
      for (int k2 = 0; k2 < 4; ++k2) {
        int idx = tid + k2 * 256;
        int jl = idx & 31, cp = idx >> 5;
        *(unsigned int*)&kB[nxt][jl * 72 + cp * 2] = pack_bf16(kf[2 * k2], kf[2 * k2 + 1]);
      }
#pragma unroll
      for (int k2 = 0; k2 < 4; ++k2) {
        int idx = tid + k2 * 256;
        int c = idx >> 4, jp = idx & 15;
        *(unsigned int*)&vA[nxt][c * 40 + jp * 2] = pack_bf16(vf[2 * k2], vf[2 * k2 + 1]);
      }
    }
    if (w == 0 && ln < QT_) {
      int row = ln;
      float m0 = mpart[0][row], m1 = mpart[1][row];
      float mn = fmaxf(m_st, fmaxf(m0, m1));
      float r_ = __expf(m_st - mn);
      float e0 = __expf(m0 - mn), e1 = __expf(m1 - mn);
      l_st = r_ * l_st + spart[0][row] * e0 + spart[1][row] * e1;
      m_st = mn;
      rf_s[row] = r_;
      efac_s[0][row] = e0;
      efac_s[1][row] = e1;
    }
    // 6. B3
    __syncthreads();
    // 7. P = pex * efac -> bf16 pack (pair via shfl) -> pP[i][j]
    float rf0 = rf_s[l15], rf1 = rf_s[16 + l15];
#pragma unroll
    for (int r = 0; r < 4; ++r) {
      float pv = pex[r] * efac_s[jt][it * 16 + 4 * g + r];
      float po = __shfl_xor(pv, 1);
      if (!(l15 & 1)) {
        *(unsigned int*)&pP[(it * 16 + 4 * g + r) * 40 + jt * 16 + l15] = pack_bf16(pv, po);
      }
    }
    // 8. B4
    __syncthreads();
    // 9. PV: rescale + 2 MFMAs (A = V[c][j], B = P^T[i][j]-as-B-frag)
    {
      short8 Va = *(const short8*)&vA[cur][(w * 16 + l15) * 40 + g * 8];
      short8 Pb0 = *(const short8*)&pP[(l15) * 40 + g * 8];
      short8 Pb1 = *(const short8*)&pP[(16 + l15) * 40 + g * 8];
#pragma unroll
      for (int r = 0; r < 4; ++r) { accO0[r] *= rf0; accO1[r] *= rf1; }
      accO0 = __builtin_amdgcn_mfma_f32_16x16x32_bf16(Va, Pb0, accO0, 0, 0, 0);
      accO1 = __builtin_amdgcn_mfma_f32_16x16x32_bf16(Va, Pb1, accO1, 0, 0, 0);
    }
  }
  // epilogue: emit m, l, O/l
  float* st = gst + (size_t)bid * GST_SZ;
  if (w == 0 && ln < QT_) {
    st[ln] = m_st;
    st[QT_ + ln] = l_st;
    l_fin[ln] = l_st;
  }
  __syncthreads();
  float inv0 = 1.0f / l_fin[l15];
  float inv1 = 1.0f / l_fin[16 + l15];
#pragma unroll
  for (int r = 0; r < 4; ++r) {
    int c = w * 16 + 4 * g + r;
    st[2 * QT_ + (size_t)c * QT_ + l15] = accO0[r] * inv0;
    st[2 * QT_ + (size_t)c * QT_ + 16 + l15] = accO1[r] * inv1;
  }
}

// ---------------- exact merge of the 2 KV-chunk states ----------------
__global__ __launch_bounds__(256) void k_gmerge(const float* __restrict__ gst,
                                                float* __restrict__ hg) {
  int bid = blockIdx.x;
  int b = bid / NQT_, qt = bid - b * NQT_;
  const float* s0 = gst + (size_t)(bid * NCH_ + 0) * GST_SZ;
  const float* s1 = gst + (size_t)(bid * NCH_ + 1) * GST_SZ;
  __shared__ float w0[QT_], w1[QT_];
  int tid = threadIdx.x;
  if (tid < QT_) {
    float m0 = s0[tid], m1 = s1[tid];
    float l0 = s0[QT_ + tid], l1 = s1[QT_ + tid];
    float m = fmaxf(m0, m1);
    float e0 = __expf(m0 - m), e1 = __expf(m1 - m);
    float linv = 1.0f / (l0 * e0 + l1 * e1);
    w0[tid] = l0 * e0 * linv; w1[tid] = l1 * e1 * linv;
  }
  __syncthreads();
  int i0 = qt * QT_;
  float* hb = hg + (size_t)b * C_ * NG_;
  for (int idx = tid; idx < 64 * QT_; idx += 256) {
    int c = idx >> 5, i = idx & 31;
    hb[(size_t)c * NG_ + i0 + i] = s0[2 * QT_ + idx] * w0[i] + s1[2 * QT_ + idx] * w1[i];
  }
}

// ---------------- final: bilinear upsample + mix + proj conv + residual ----------------
__global__ __launch_bounds__(256) void k_final(const float* __restrict__ xin,
                                               const float* __restrict__ hp,
                                               const float* __restrict__ hg,
                                               const float* __restrict__ wpT,
                                               float* __restrict__ out) {
  int b = blockIdx.x / S_, y = blockIdx.x - (blockIdx.x / S_) * S_;
  __shared__ float hmix[64 * 112];
  __shared__ float wps[4096];
  int tid = threadIdx.x;
  for (int idx = tid; idx < 4096; idx += 256) wps[idx] = wpT[idx];
  int th = y >> 1, r = y & 1;
  int y0 = r ? th : (th > 0 ? th - 1 : 0);
  int y1 = r ? (th < TG_ - 1 ? th + 1 : TG_ - 1) : th;
  float wy0 = r ? 0.75f : 0.25f;
  float wy1 = 1.0f - wy0;
  const float* hgb = hg + (size_t)b * C_ * NG_;
  const float* hpb = hp + (size_t)b * C_ * HW_;
  for (int idx = tid; idx < 64 * 112; idx += 256) {
    int c = idx / S_, xx = idx - c * S_;
    int u = xx >> 1, sx = xx & 1;
    int x0 = sx ? u : (u > 0 ? u - 1 : 0);
    int x1 = sx ? (u < TG_ - 1 ? u + 1 : TG_ - 1) : u;
    float wx0 = sx ? 0.75f : 0.25f;
    float wx1 = 1.0f - wx0;
    const float* g = hgb + (size_t)c * NG_;
    float up = wy0 * (wx0 * g[y0 * TG_ + x0] + wx1 * g[y0 * TG_ + x1])
             + wy1 * (wx0 * g[y1 * TG_ + x0] + wx1 * g[y1 * TG_ + x1]);
    hmix[idx] = 0.75f * hpb[(size_t)c * HW_ + (size_t)y * S_ + xx] + 0.25f * up;
  }
  __syncthreads();
  int o = tid & 63, gq = tid >> 6;
  float acc[28];
#pragma unroll
  for (int t = 0; t < 28; ++t) acc[t] = 0.f;
  for (int c = 0; c < 64; ++c) {
    float wv = wps[c * 64 + o];
    const float4* hrow = (const float4*)(hmix + c * S_ + gq * 28);
#pragma unroll
    for (int t4 = 0; t4 < 7; ++t4) {
      float4 h4 = hrow[t4];
      acc[t4*4+0] += wv * h4.x; acc[t4*4+1] += wv * h4.y;
      acc[t4*4+2] += wv * h4.z; acc[t4*4+3] += wv * h4.w;
    }
  }
  size_t ob = ((size_t)(b * 64 + o)) * HW_ + (size_t)y * S_ + gq * 28;
  const float4* xr = (const float4*)(xin + ob);
  float4* od = (float4*)(out + ob);
#pragma unroll
  for (int t4 = 0; t4 < 7; ++t4) {
    float4 xv = xr[t4];
    od[t4] = make_float4(xv.x + acc[t4*4], xv.y + acc[t4*4+1],
                         xv.z + acc[t4*4+2], xv.w + acc[t4*4+3]);
  }
}

extern "C" void kernel_launch(void* const* d_in, const int* in_sizes, int n_in,
                              void* d_out, int out_size, void* d_ws, size_t ws_size,
                              hipStream_t stream) {
  (void)in_sizes; (void)n_in; (void)out_size; (void)ws_size;
  const float* x   = (const float*)d_in[0];
  const float* gnw = (const float*)d_in[1];
  const float* gnb = (const float*)d_in[2];
  const float* wq  = (const float*)d_in[3];
  const float* bq  = (const float*)d_in[4];
  const float* wk  = (const float*)d_in[5];
  const float* bk  = (const float*)d_in[6];
  const float* wv  = (const float*)d_in[7];
  const float* bv  = (const float*)d_in[8];
  const float* wp  = (const float*)d_in[9];
  float* out = (float*)d_out;
  float* ws  = (float*)d_ws;

  hipMemsetAsync(d_ws, 0, OFF_WQT * sizeof(float), stream);

  k_wtrans<<<16, 256, 0, stream>>>(wq, wk, wv, wp,
                                   ws + OFF_WQT, ws + OFF_WKT, ws + OFF_WVT, ws + OFF_WPT);
  k_gnstats<<<B_ * C_, 256, 0, stream>>>(x, ws + OFF_STATS);
  k_qkv<<<B_ * PA_, 256, 0, stream>>>(x, ws + OFF_STATS, gnw, gnb,
                                      ws + OFF_WQT, ws + OFF_WKT, ws + OFF_WVT,
                                      bq, bk, bv,
                                      ws + OFF_Q, ws + OFF_K, ws + OFF_V);
  k_pool<<<(B_ * C_ * NG_ + 255) / 256, 256, 0, stream>>>(
      ws + OFF_Q, ws + OFF_K, ws + OFF_V, ws + OFF_QG, ws + OFF_KG, ws + OFF_VG);
  k_pqk<<<B_ * 64, 256, 0, stream>>>(ws + OFF_Q, ws + OFF_K, ws + OFF_SP);
  k_psoftmax<<<B_ * PA_, 64, 0, stream>>>(ws + OFF_SP, ws + OFF_WT);
  k_pav<<<B_ * 64, 256, 0, stream>>>(ws + OFF_V, ws + OFF_WT, ws + OFF_HP);
  k_gattn_part<<<B_ * NQT_ * NCH_, 256, 0, stream>>>(ws + OFF_QG, ws + OFF_KG, ws + OFF_VG,
                                                     ws + OFF_GST);
  k_gmerge<<<B_ * NQT_, 256, 0, stream>>>(ws + OFF_GST, ws + OFF_HG);
  k_final<<<B_ * S_, 256, 0, stream>>>(x, ws + OFF_HP, ws + OFF_HG, ws + OFF_WPT, out);
}